// Round 14
// baseline (173.300 us; speedup 1.0000x reference)
//
#include <hip/hip_runtime.h>
#include <stdint.h>
#include <stddef.h>

#define AS1 __attribute__((address_space(1)))
#define AS3 __attribute__((address_space(3)))

typedef short bf16x8 __attribute__((ext_vector_type(8)));
typedef float f32x4 __attribute__((ext_vector_type(4)));
typedef unsigned short u16x8 __attribute__((ext_vector_type(8)));

static constexpr int N = 4096;
static constexpr int K = 2048;
static constexpr int BM = 128;         // legacy fallback tile
static constexpr int TILES = N / BM;   // 32
static constexpr int NBLK = TILES * TILES;  // 1024 (fallback)

// round-to-nearest-even f32 -> bf16
__device__ __forceinline__ unsigned short f2bf(float f) {
  union { float f; uint32_t u; } v; v.f = f;
  return (unsigned short)((v.u + 0x7FFFu + ((v.u >> 16) & 1u)) >> 16);
}

__global__ __launch_bounds__(256) void prep_kernel(
    const float* __restrict__ X, const float* __restrict__ Y,
    float* __restrict__ x2, float* __restrict__ y2,
    unsigned short* __restrict__ Xb, unsigned short* __restrict__ Yb, int wb) {
  const int row = blockIdx.x;
  const float* src = blockIdx.y ? Y : X;
  float* nrm = blockIdx.y ? y2 : x2;
  unsigned short* dst = blockIdx.y ? Yb : Xb;
  const size_t base = (size_t)row * K + threadIdx.x * 8;
  const float4 a = *(const float4*)(src + base);
  const float4 b = *(const float4*)(src + base + 4);
  double s = (double)a.x * a.x + (double)a.y * a.y + (double)a.z * a.z +
             (double)a.w * a.w + (double)b.x * b.x + (double)b.y * b.y +
             (double)b.z * b.z + (double)b.w * b.w;
  if (wb) {
    u16x8 o;
    o[0] = f2bf(a.x); o[1] = f2bf(a.y); o[2] = f2bf(a.z); o[3] = f2bf(a.w);
    o[4] = f2bf(b.x); o[5] = f2bf(b.y); o[6] = f2bf(b.z); o[7] = f2bf(b.w);
    *(u16x8*)(dst + base) = o;
  }
#pragma unroll
  for (int off = 32; off; off >>= 1) s += __shfl_down(s, off);
  __shared__ double red[4];
  if ((threadIdx.x & 63) == 0) red[threadIdx.x >> 6] = s;
  __syncthreads();
  if (threadIdx.x == 0) nrm[row] = (float)(red[0] + red[1] + red[2] + red[3]);
}

// -------- merged engine: 592 blocks = 96 light 128^2 FIRST + 496 heavy -----
// LIGHT (bid 0..95, dispatched first — r13 packing):
//   diag 256-tile quadrants: pair p x d(0..15) x sub{d00 w1, d01 w2, d11 w1},
//   128^2 output, 8 waves (2Mx4N of 64x32), simple 2-barrier loop.
// HEAVY (bid 96..591), lg = (((bid-96)&7)*62 + ((bid-96)>>3)) bijective:
//   lg 0..255:   XY tile (ti=lg&15, tj=lg>>4), w = -2
//   lg 256..375: XX strict-upper off-diag (ti<tj), w = +2 (exact mirror)
//   lg 376..495: YY strict-upper off-diag,          w = +2
// Heavy LDS: RB3(buf,O) = buf*32768 + O*16384 shorts; region 256 rows x 64 K
// (128B rows, 8 chunks of 16B), chunk c at slot c ^ (r&7) (conflict-free,
// r9: SQ_LDS_BANK_CONFLICT == 0). Source pre-swizzled; gload_lds dest linear.
// r14 BALANCED-READ schedule: phases by (ks, mi-half), 16 MFMA each
// (4 mi x 4 ni); read bursts 4/8/4/8 (was 2/10/2/10 -> the 10-read phases
// stalled the next lgkmcnt(0) by ~150-300cy). Regs: afA[4]/afB[4] ping-pong
// + b0..b3 (k-slice, live 2 phases; WAR overwrite after MFMA is in-order-safe).
//   P1: MFMA(afA=k0m03) | rd afB=A(k0m47)        | stg A(t+1)h1,B(t+1)h0->b^1
//   P2: MFMA(afB=k0m47) | rd afA=A(k1m03), b=B(k1)| stg B(t+1)h1->b^1
//   P3: MFMA(afA=k1m03) | rd afB=A(k1m47)        | (no stage)
//   P4: MFMA(afB=k1m47) | stg A(t+2)h0->b ; vmcnt(2) ; rd afA,b = tile t+1 @b^1
// FIFO ledger (identical slots to r12-verified): entering P1 in-flight=2
// [A(t+1)h0]; +4/+2/+0/+2; vmcnt(2)@P4 retires all 8 of tile t+1 => P4
// prefetch reads resident. A[b] dies P3 (stage at P4 is 1 barrier + full
// MFMA cluster later); B[b] dies P4; all targets dead at stage (incl. tail).
// NOTE: occupancy register-bound at 2 waves/SIMD (1 block/CU); 128KB LDS
// free. __launch_bounds__ 2nd arg stays 2 (r7: arg=4 => 64-VGPR cap =>
// 4.3GB scratch spills, 7.9x slower).

#define RB3(bb, o) ((unsigned)((bb)*32768u + (o)*16384u))
#define VM2 asm volatile("s_waitcnt vmcnt(2)" ::: "memory")
#define LGKM0                                                                  \
  do {                                                                         \
    asm volatile("s_waitcnt lgkmcnt(0)" ::: "memory");                         \
    __builtin_amdgcn_sched_barrier(0);                                         \
  } while (0)

#define STG(O, TT, BB, H)                                                      \
  do {                                                                         \
    const unsigned short* _sp = (O) ? Bpan : Apan;                             \
    const unsigned int _so =                                                   \
        ((O) ? sB : sA) + (unsigned)(H) * 262144u + (unsigned)(TT) * 64u;      \
    const unsigned int _lb = RB3(BB, O) + (unsigned)(H) * 8192u + wseg;        \
    __builtin_amdgcn_global_load_lds(                                          \
        (const AS1 unsigned int*)(_sp + _so),                                  \
        (AS3 unsigned int*)(lds + _lb), 16, 0, 0);                             \
    __builtin_amdgcn_global_load_lds(                                          \
        (const AS1 unsigned int*)(_sp + _so + 16384u),                         \
        (AS3 unsigned int*)(lds + _lb + 512u), 16, 0, 0);                      \
  } while (0)

// read one A mi-half (4 frags) from k-slice KS of buf BB into DST
#define RDAH(DST, BASE, KS, BB)                                                \
  _Pragma("unroll") for (int _q = 0; _q < 4; ++_q)                             \
      DST[_q] = *(const bf16x8*)(lds + RB3(BB, 0) +                            \
                                 (aoff[(BASE) + _q] ^ ((KS) * 32u)))

// read all 4 B frags from k-slice KS of buf BB into b0..b3
#define RDB4(KS, BB)                                                           \
  do {                                                                         \
    b0 = *(const bf16x8*)(lds + RB3(BB, 1) + (boff[0] ^ ((KS) * 32u)));        \
    b1 = *(const bf16x8*)(lds + RB3(BB, 1) + (boff[1] ^ ((KS) * 32u)));        \
    b2 = *(const bf16x8*)(lds + RB3(BB, 1) + (boff[2] ^ ((KS) * 32u)));        \
    b3 = *(const bf16x8*)(lds + RB3(BB, 1) + (boff[3] ^ ((KS) * 32u)));        \
  } while (0)

// 16 MFMA: mi-half MH (rows MH*4..MH*4+3) x all 4 ni columns
#define MFMA_H(AF, MH)                                                         \
  do {                                                                         \
    __builtin_amdgcn_s_setprio(1);                                             \
    _Pragma("unroll") for (int _mi = 0; _mi < 4; ++_mi) {                      \
      acc[(MH) * 4 + _mi][0] = __builtin_amdgcn_mfma_f32_16x16x32_bf16(        \
          AF[_mi], b0, acc[(MH) * 4 + _mi][0], 0, 0, 0);                       \
      acc[(MH) * 4 + _mi][1] = __builtin_amdgcn_mfma_f32_16x16x32_bf16(        \
          AF[_mi], b1, acc[(MH) * 4 + _mi][1], 0, 0, 0);                       \
      acc[(MH) * 4 + _mi][2] = __builtin_amdgcn_mfma_f32_16x16x32_bf16(        \
          AF[_mi], b2, acc[(MH) * 4 + _mi][2], 0, 0, 0);                       \
      acc[(MH) * 4 + _mi][3] = __builtin_amdgcn_mfma_f32_16x16x32_bf16(        \
          AF[_mi], b3, acc[(MH) * 4 + _mi][3], 0, 0, 0);                       \
    }                                                                          \
    __builtin_amdgcn_s_setprio(0);                                             \
  } while (0)

#define TILE5(T, BB)                                                           \
  do {                                                                         \
    const int _t1 = ((T) + 1 < 32) ? (T) + 1 : 31;                             \
    const int _t2 = ((T) + 2 < 32) ? (T) + 2 : 31;                             \
    /* P1: k0, m0-3 */                                                         \
    LGKM0; MFMA_H(afA, 0);                                                     \
    RDAH(afB, 4, 0, BB);                                                       \
    STG(0, _t1, 1 - (BB), 1); STG(1, _t1, 1 - (BB), 0);                        \
    __builtin_amdgcn_s_barrier();                                              \
    /* P2: k0, m4-7 */                                                         \
    LGKM0; MFMA_H(afB, 1);                                                     \
    RDAH(afA, 0, 1, BB); RDB4(1, BB);                                          \
    STG(1, _t1, 1 - (BB), 1);                                                  \
    __builtin_amdgcn_s_barrier();                                              \
    /* P3: k1, m0-3 */                                                         \
    LGKM0; MFMA_H(afA, 0);                                                     \
    RDAH(afB, 4, 1, BB);                                                       \
    __builtin_amdgcn_s_barrier();                                              \
    /* P4: k1, m4-7 */                                                         \
    LGKM0; MFMA_H(afB, 1);                                                     \
    STG(0, _t2, (BB), 0);                                                      \
    VM2;                                                                       \
    RDAH(afA, 0, 0, 1 - (BB)); RDB4(0, 1 - (BB));                              \
    __builtin_amdgcn_s_barrier();                                              \
  } while (0)

__global__ __launch_bounds__(512, 2) void mmd_gemm8(
    const unsigned short* __restrict__ Xb, const unsigned short* __restrict__ Yb,
    const float* __restrict__ x2, const float* __restrict__ y2,
    double* __restrict__ partials) {
  __shared__ __align__(16) unsigned short lds[65536];  // 128 KiB
  __shared__ double red[8];

  const int bid = blockIdx.x;                       // 592 blocks
  const int tid = threadIdx.x;
  const int w = tid >> 6, l = tid & 63;
  const int lr = l & 15, lq = l >> 4;
  const float ce = -1.0f / (2048.0f * 2048.0f);

  if (bid >= 96) {
    // =============================== HEAVY ===============================
    const int hb = bid - 96;
    const int logical = (hb & 7) * 62 + (hb >> 3);
    int ti, tj;
    const unsigned short *Apan, *Bpan;
    const float *rn, *cn;
    double wgt;
    if (logical < 256) {            // XY
      ti = logical & 15; tj = logical >> 4;
      Apan = Xb; Bpan = Yb; rn = x2; cn = y2; wgt = -2.0;
    } else {                        // XX/YY strict-upper off-diagonal
      const int q = logical - 256;
      const int pp = q / 120;
      int jj = q % 120;
      int rr = 0;
      while (jj >= 15 - rr) { jj -= 15 - rr; ++rr; }
      ti = rr; tj = rr + 1 + jj;    // ti < tj
      Apan = Bpan = pp ? Yb : Xb;
      rn = cn = pp ? y2 : x2;
      wgt = 2.0;
    }
    const int i0 = ti << 8, j0 = tj << 8;
    const int wm = w >> 2, wn = w & 3;

    const int ci = w * 128 + l;
    const int rr0 = ci >> 3;
    const int cc0 = (ci & 7) ^ (rr0 & 7);
    const unsigned int sA = (unsigned)(i0 + rr0) * (unsigned)K + (unsigned)(cc0 * 8);
    const unsigned int sB = (unsigned)(j0 + rr0) * (unsigned)K + (unsigned)(cc0 * 8);
    const unsigned int wseg = (unsigned)w * 1024u;

    unsigned int aoff[8], boff[4];
#pragma unroll
    for (int mi = 0; mi < 8; ++mi) {
      const int r = wm * 128 + mi * 16 + lr;
      aoff[mi] = (unsigned)(r * 64 + ((lq ^ (r & 7)) * 8));
    }
#pragma unroll
    for (int ni = 0; ni < 4; ++ni) {
      const int rb = wn * 64 + ni * 16 + lr;
      boff[ni] = (unsigned)(rb * 64 + ((lq ^ (rb & 7)) * 8));
    }

    f32x4 acc[8][4] = {};
    bf16x8 afA[4], afB[4], b0, b1, b2, b3;

    // Prologue: A(0) h0,h1; B(0) h0,h1; A(1) h0 — retire all but A(1)h0,
    // then issue P1's operand reads (waited at the loop's first LGKM0).
    STG(0, 0, 0, 0); STG(0, 0, 0, 1); STG(1, 0, 0, 0); STG(1, 0, 0, 1);
    STG(0, 1, 1, 0);
    VM2;
    __builtin_amdgcn_s_barrier();
    RDAH(afA, 0, 0, 0); RDB4(0, 0);

#pragma unroll 1
    for (int tt = 0; tt < 32; tt += 2) {
      TILE5(tt, 0);
      TILE5(tt + 1, 1);
    }

    double s = 0.0;
#pragma unroll
    for (int mi = 0; mi < 8; ++mi) {
#pragma unroll
      for (int r4 = 0; r4 < 4; ++r4) {
        const float rv = rn[i0 + wm * 128 + mi * 16 + lq * 4 + r4];
#pragma unroll
        for (int ni = 0; ni < 4; ++ni) {
          const float cv = cn[j0 + wn * 64 + ni * 16 + lr];
          const float tx = ce * (rv + cv - 2.0f * acc[mi][ni][r4]);
          const float v =
              tx * (1.0f + tx * (0.5f + tx * (0.16666667f + tx * 0.041666668f)));
          s += (double)v;
        }
      }
    }
#pragma unroll
    for (int off = 32; off; off >>= 1) s += __shfl_down(s, off);
    if (l == 0) red[w] = s;
    __syncthreads();
    if (tid == 0) {
      double tot = 0.0;
#pragma unroll
      for (int i = 0; i < 8; ++i) tot += red[i];
      partials[logical] = wgt * tot;
    }
  } else {
    // =============================== LIGHT ===============================
    // diag-quadrant 128^2 jobs; 8 waves of 64x32; LDS: A 0..8192, B 8192..16384
    const int lg2 = (bid & 7) * 12 + (bid >> 3);  // bijective XCD spread (96=8x12)
    const int p = lg2 / 48;
    const int rem = lg2 % 48;
    const int d = rem / 3, sub = rem % 3;
    const double wgt = (sub == 1) ? 2.0 : 1.0;
    const unsigned short* Pan = p ? Yb : Xb;
    const float* nrm = p ? y2 : x2;
    const int i0 = d * 256 + ((sub == 2) ? 128 : 0);
    const int j0 = d * 256 + ((sub >= 1) ? 128 : 0);

    const int m_b = (w >> 2) * 64, n_b = (w & 3) * 32;

    // staging: 1024 16B chunks per operand; thread covers ci0l and ci0l+512
    const int ci0l = w * 64 + l, ci1l = ci0l + 512;
    const int rA0 = ci0l >> 3, cA0 = (ci0l & 7) ^ (rA0 & 7);
    const int rA1 = ci1l >> 3, cA1 = (ci1l & 7) ^ (rA1 & 7);
    const unsigned int sLA0 = (unsigned)(i0 + rA0) * K + (unsigned)(cA0 * 8);
    const unsigned int sLA1 = (unsigned)(i0 + rA1) * K + (unsigned)(cA1 * 8);
    const unsigned int sLB0 = (unsigned)(j0 + rA0) * K + (unsigned)(cA0 * 8);
    const unsigned int sLB1 = (unsigned)(j0 + rA1) * K + (unsigned)(cA1 * 8);
    const unsigned int d0 = (unsigned)w * 512u, d1 = 4096u + (unsigned)w * 512u;

    f32x4 acc2[4][2] = {};

#pragma unroll 1
    for (int k0 = 0; k0 < K; k0 += 64) {
      __builtin_amdgcn_global_load_lds((const AS1 unsigned int*)(Pan + sLA0 + k0),
                                       (AS3 unsigned int*)(lds + d0), 16, 0, 0);
      __builtin_amdgcn_global_load_lds((const AS1 unsigned int*)(Pan + sLA1 + k0),
                                       (AS3 unsigned int*)(lds + d1), 16, 0, 0);
      __builtin_amdgcn_global_load_lds((const AS1 unsigned int*)(Pan + sLB0 + k0),
                                       (AS3 unsigned int*)(lds + 8192u + d0), 16, 0, 0);
      __builtin_amdgcn_global_load_lds((const AS1 unsigned int*)(Pan + sLB1 + k0),
                                       (AS3 unsigned int*)(lds + 8192u + d1), 16, 0, 0);
      __syncthreads();
#pragma unroll
      for (int kk = 0; kk < 64; kk += 32) {
        const int ch = (kk >> 3) + lq;
        bf16x8 a2[4], bb[2];
#pragma unroll
        for (int mi = 0; mi < 4; ++mi) {
          const int r = m_b + mi * 16 + lr;
          a2[mi] = *(const bf16x8*)(lds + r * 64 + ((ch ^ (r & 7)) * 8));
        }
#pragma unroll
        for (int ni = 0; ni < 2; ++ni) {
          const int r = n_b + ni * 16 + lr;
          bb[ni] = *(const bf16x8*)(lds + 8192 + r * 64 + ((ch ^ (r & 7)) * 8));
        }
#pragma unroll
        for (int mi = 0; mi < 4; ++mi)
#pragma unroll
          for (int ni = 0; ni < 2; ++ni)
            acc2[mi][ni] = __builtin_amdgcn_mfma_f32_16x16x32_bf16(
                a2[mi], bb[ni], acc2[mi][ni], 0, 0, 0);
      }
      __syncthreads();
    }

    double s = 0.0;
#pragma unroll
    for (int mi = 0; mi < 4; ++mi) {
#pragma unroll
      for (int r4 = 0; r4 < 4; ++r4) {
        const float rv = nrm[i0 + m_b + mi * 16 + lq * 4 + r4];
#pragma unroll
        for (int ni = 0; ni < 2; ++ni) {
          const float cv = nrm[j0 + n_b + ni * 16 + lr];
          const float tx = ce * (rv + cv - 2.0f * acc2[mi][ni][r4]);
          const float v =
              tx * (1.0f + tx * (0.5f + tx * (0.16666667f + tx * 0.041666668f)));
          s += (double)v;
        }
      }
    }
#pragma unroll
    for (int off = 32; off; off >>= 1) s += __shfl_down(s, off);
    if (l == 0) red[w] = s;
    __syncthreads();
    if (tid == 0) {
      double tot = 0.0;
#pragma unroll
      for (int i = 0; i < 8; ++i) tot += red[i];
      partials[496 + lg2] = wgt * tot;
    }
  }
}

// ---------------- legacy 128^2 kernel (ws-too-small fallback, f32 inputs) ----
__global__ __launch_bounds__(256) void mmd_gemm_f32(
    const float* __restrict__ Xp, const float* __restrict__ Yp,
    const float* __restrict__ x2, const float* __restrict__ y2,
    double* __restrict__ partials) {
  const int p = blockIdx.y;
  const float* Ap = (p == 1) ? Yp : Xp;
  const float* Bp = (p == 0) ? Xp : Yp;
  const float* rn = (p == 1) ? y2 : x2;
  const float* cn = (p == 0) ? x2 : y2;
  const double wgt = (p == 2) ? -2.0 : 1.0;

  const int bx = blockIdx.x;
  const int i0 = (bx & (TILES - 1)) * BM;
  const int j0 = (bx / TILES) * BM;

  __shared__ __align__(16) unsigned short As[BM * 64];
  __shared__ __align__(16) unsigned short Bs[BM * 64];

  const int tid = threadIdx.x;
  const int w = tid >> 6, l = tid & 63;
  const int m_base = (w >> 1) * 64, n_base = (w & 1) * 64;

  f32x4 acc[4][4] = {};

  for (int k0 = 0; k0 < K; k0 += 64) {
#pragma unroll
    for (int u = 0; u < 4; ++u) {
      const int f = u * 256 + tid;
      const int row = f >> 3;
      const int cir = f & 7;
      const int dstb = row * 128 + ((cir ^ (row & 7)) * 16);
      {
        const float* g = Ap + (size_t)(i0 + row) * K + k0 + cir * 8;
        const float4 v0 = *(const float4*)g;
        const float4 v1 = *(const float4*)(g + 4);
        u16x8 o;
        o[0] = f2bf(v0.x); o[1] = f2bf(v0.y); o[2] = f2bf(v0.z); o[3] = f2bf(v0.w);
        o[4] = f2bf(v1.x); o[5] = f2bf(v1.y); o[6] = f2bf(v1.z); o[7] = f2bf(v1.w);
        *(u16x8*)((char*)As + dstb) = o;
      }
      {
        const float* g = Bp + (size_t)(j0 + row) * K + k0 + cir * 8;
        const float4 v0 = *(const float4*)g;
        const float4 v1 = *(const float4*)(g + 4);
        u16x8 o;
        o[0] = f2bf(v0.x); o[1] = f2bf(v0.y); o[2] = f2bf(v0.z); o[3] = f2bf(v0.w);
        o[4] = f2bf(v1.x); o[5] = f2bf(v1.y); o[6] = f2bf(v1.z); o[7] = f2bf(v1.w);
        *(u16x8*)((char*)Bs + dstb) = o;
      }
    }
    __syncthreads();

#pragma unroll
    for (int kk = 0; kk < 64; kk += 32) {
      bf16x8 af2[4], bfr[4];
      const int lr = l & 15;
      const int ch = (kk >> 3) + (l >> 4);
#pragma unroll
      for (int mi = 0; mi < 4; ++mi) {
        const int r = m_base + mi * 16 + lr;
        af2[mi] = *(const bf16x8*)((const char*)As + r * 128 + ((ch ^ (r & 7)) * 16));
      }
#pragma unroll
      for (int ni = 0; ni < 4; ++ni) {
        const int r = n_base + ni * 16 + lr;
        bfr[ni] = *(const bf16x8*)((const char*)Bs + r * 128 + ((ch ^ (r & 7)) * 16));
      }
#pragma unroll
      for (int mi = 0; mi < 4; ++mi)
#pragma unroll
        for (int ni = 0; ni < 4; ++ni)
          acc[mi][ni] = __builtin_amdgcn_mfma_f32_16x16x32_bf16(
              af2[mi], bfr[ni], acc[mi][ni], 0, 0, 0);
    }
    __syncthreads();
  }

  const float ce = -1.0f / (2048.0f * 2048.0f);
  double s = 0.0;
  const int lr = l & 15, lq = l >> 4;
#pragma unroll
  for (int mi = 0; mi < 4; ++mi) {
#pragma unroll
    for (int r4 = 0; r4 < 4; ++r4) {
      const float rv = rn[i0 + m_base + mi * 16 + lq * 4 + r4];
#pragma unroll
      for (int ni = 0; ni < 4; ++ni) {
        const float cv = cn[j0 + n_base + ni * 16 + lr];
        const float tx = ce * (rv + cv - 2.0f * acc[mi][ni][r4]);
        const float v =
            tx * (1.0f + tx * (0.5f + tx * (0.16666667f + tx * 0.041666668f)));
        s += (double)v;
      }
    }
  }
#pragma unroll
  for (int off = 32; off; off >>= 1) s += __shfl_down(s, off);
  __shared__ double red[4];
  if (l == 0) red[w] = s;
  __syncthreads();
  if (tid == 0) partials[p * NBLK + bx] = wgt * (red[0] + red[1] + red[2] + red[3]);
}

__global__ __launch_bounds__(256) void finalize_kernel(
    const double* __restrict__ partials, float* __restrict__ out, int n) {
  double s = 0.0;
  for (int i = threadIdx.x; i < n; i += 256) s += partials[i];
#pragma unroll
  for (int off = 32; off; off >>= 1) s += __shfl_down(s, off);
  __shared__ double red[4];
  if ((threadIdx.x & 63) == 0) red[threadIdx.x >> 6] = s;
  __syncthreads();
  if (threadIdx.x == 0)
    out[0] = (float)((red[0] + red[1] + red[2] + red[3]) *
                     (1.0 / ((double)N * (double)N)));
}

extern "C" void kernel_launch(void* const* d_in, const int* in_sizes, int n_in,
                              void* d_out, int out_size, void* d_ws,
                              size_t ws_size, hipStream_t stream) {
  const float* X = (const float*)d_in[0];
  const float* Y = (const float*)d_in[1];
  char* ws = (char*)d_ws;

  double* partials = (double*)ws;           // fast: 592 f64; fallback: 3072
  float* x2 = (float*)(ws + 24576);
  float* y2 = (float*)(ws + 24576 + 16384);
  unsigned short* Xb = (unsigned short*)(ws + 65536);
  unsigned short* Yb = Xb + (size_t)N * K;
  const size_t need_fast = (size_t)65536 + (size_t)2 * N * K * 2;
  const bool fast = ws_size >= need_fast;

  prep_kernel<<<dim3(N, 2), 256, 0, stream>>>(X, Y, x2, y2, Xb, Yb, fast ? 1 : 0);
  if (fast) {
    mmd_gemm8<<<dim3(592), dim3(512), 0, stream>>>(Xb, Yb, x2, y2, partials);
    finalize_kernel<<<1, 256, 0, stream>>>(partials, (float*)d_out, 592);
  } else {
    mmd_gemm_f32<<<dim3(NBLK, 3), 256, 0, stream>>>(X, Y, x2, y2, partials);
    finalize_kernel<<<1, 256, 0, stream>>>(partials, (float*)d_out, 3072);
  }
}

// Round 15
// 162.789 us; speedup vs baseline: 1.0646x; 1.0646x over previous
//
#include <hip/hip_runtime.h>
#include <stdint.h>
#include <stddef.h>

#define AS1 __attribute__((address_space(1)))
#define AS3 __attribute__((address_space(3)))

typedef short bf16x8 __attribute__((ext_vector_type(8)));
typedef float f32x4 __attribute__((ext_vector_type(4)));
typedef unsigned short u16x8 __attribute__((ext_vector_type(8)));

static constexpr int N = 4096;
static constexpr int K = 2048;
static constexpr int BM = 128;         // legacy fallback tile
static constexpr int TILES = N / BM;   // 32
static constexpr int NBLK = TILES * TILES;  // 1024 (fallback)

// round-to-nearest-even f32 -> bf16
__device__ __forceinline__ unsigned short f2bf(float f) {
  union { float f; uint32_t u; } v; v.f = f;
  return (unsigned short)((v.u + 0x7FFFu + ((v.u >> 16) & 1u)) >> 16);
}

__global__ __launch_bounds__(256) void prep_kernel(
    const float* __restrict__ X, const float* __restrict__ Y,
    float* __restrict__ x2, float* __restrict__ y2,
    unsigned short* __restrict__ Xb, unsigned short* __restrict__ Yb, int wb) {
  const int row = blockIdx.x;
  const float* src = blockIdx.y ? Y : X;
  float* nrm = blockIdx.y ? y2 : x2;
  unsigned short* dst = blockIdx.y ? Yb : Xb;
  const size_t base = (size_t)row * K + threadIdx.x * 8;
  const float4 a = *(const float4*)(src + base);
  const float4 b = *(const float4*)(src + base + 4);
  double s = (double)a.x * a.x + (double)a.y * a.y + (double)a.z * a.z +
             (double)a.w * a.w + (double)b.x * b.x + (double)b.y * b.y +
             (double)b.z * b.z + (double)b.w * b.w;
  if (wb) {
    u16x8 o;
    o[0] = f2bf(a.x); o[1] = f2bf(a.y); o[2] = f2bf(a.z); o[3] = f2bf(a.w);
    o[4] = f2bf(b.x); o[5] = f2bf(b.y); o[6] = f2bf(b.z); o[7] = f2bf(b.w);
    *(u16x8*)(dst + base) = o;
  }
#pragma unroll
  for (int off = 32; off; off >>= 1) s += __shfl_down(s, off);
  __shared__ double red[4];
  if ((threadIdx.x & 63) == 0) red[threadIdx.x >> 6] = s;
  __syncthreads();
  if (threadIdx.x == 0) nrm[row] = (float)(red[0] + red[1] + red[2] + red[3]);
}

// -------- merged engine: 592 blocks = 96 light 128^2 FIRST + 496 heavy -----
// BEST CONFIG (r13, 163.3us). r14's balanced-read re-phasing (4/8/4/8 with
// mi-half MFMA clusters) REGRESSED to 173us — read-to-use distance, not
// burst size, is what matters; this TILE4 shifted-read schedule maximizes it.
// LIGHT (bid 0..95, dispatched first — r13 packing):
//   diag 256-tile quadrants: pair p x d(0..15) x sub{d00 w1, d01 w2, d11 w1},
//   128^2 output, 8 waves (2Mx4N of 64x32), simple 2-barrier loop.
// HEAVY (bid 96..591), lg = (((bid-96)&7)*62 + ((bid-96)>>3)) bijective:
//   lg 0..255:   XY tile (ti=lg&15, tj=lg>>4), w = -2
//   lg 256..375: XX strict-upper off-diag (ti<tj), w = +2 (exact mirror)
//   lg 376..495: YY strict-upper off-diag,          w = +2
// Heavy LDS: RB3(buf,O) = buf*32768 + O*16384 shorts; region 256 rows x 64 K
// (128B rows, 8 chunks of 16B), chunk c at slot c ^ (r&7) (conflict-free,
// r9: SQ_LDS_BANK_CONFLICT == 0). Source pre-swizzled; gload_lds dest linear.
// Shifted-read schedule (r11) + deepened B prefetch (r12):
//   P1: MFMA(k0,n01) | rd b2,b3(k0)       | stg A(t+1)h1, B(t+1)h0 -> b^1
//   P2: MFMA(k0,n23) | rd af(k1),b0,b1(k1)| stg B(t+1)h1 -> b^1
//   P3: MFMA(k1,n01) | rd b2,b3(k1)       | (no stage)
//   P4: MFMA(k1,n23) | stg A(t+2)h0 -> b ; vmcnt(2) ; rd af,b0,b1(k0)@b^1
// FIFO ledger: entering P1 in-flight=2 [A(t+1)h0]; +4/+2/+0/+2; vmcnt(2)@P4
// retires all 8 of tile t+1 (leaves A(t+2)h0) => P4 prefetch reads resident.
// Region deaths: A[b] P2, B[b] P3; every stage >=2 barriers past target death
// (incl. clamped tail).
// NOTE: occupancy register-bound at 2 waves/SIMD (1 block/CU); 128KB LDS
// free. __launch_bounds__ 2nd arg stays 2 (r7: arg=4 => 64-VGPR cap =>
// 4.3GB scratch spills, 7.9x slower).

#define RB3(bb, o) ((unsigned)((bb)*32768u + (o)*16384u))
#define VM2 asm volatile("s_waitcnt vmcnt(2)" ::: "memory")
#define LGKM0                                                                  \
  do {                                                                         \
    asm volatile("s_waitcnt lgkmcnt(0)" ::: "memory");                         \
    __builtin_amdgcn_sched_barrier(0);                                         \
  } while (0)

#define STG(O, TT, BB, H)                                                      \
  do {                                                                         \
    const unsigned short* _sp = (O) ? Bpan : Apan;                             \
    const unsigned int _so =                                                   \
        ((O) ? sB : sA) + (unsigned)(H) * 262144u + (unsigned)(TT) * 64u;      \
    const unsigned int _lb = RB3(BB, O) + (unsigned)(H) * 8192u + wseg;        \
    __builtin_amdgcn_global_load_lds(                                          \
        (const AS1 unsigned int*)(_sp + _so),                                  \
        (AS3 unsigned int*)(lds + _lb), 16, 0, 0);                             \
    __builtin_amdgcn_global_load_lds(                                          \
        (const AS1 unsigned int*)(_sp + _so + 16384u),                         \
        (AS3 unsigned int*)(lds + _lb + 512u), 16, 0, 0);                      \
  } while (0)

#define RDA(KS, BB)                                                            \
  _Pragma("unroll") for (int _mi = 0; _mi < 8; ++_mi)                          \
      af[_mi] = *(const bf16x8*)(lds + RB3(BB, 0) + (aoff[_mi] ^ ((KS) * 32u)))

#define RDB(VAR, IDX, KS, BB)                                                  \
  VAR = *(const bf16x8*)(lds + RB3(BB, 1) + (boff[IDX] ^ ((KS) * 32u)))

#define MFMA_P(X0, X1, C0, C1)                                                 \
  do {                                                                         \
    __builtin_amdgcn_s_setprio(1);                                             \
    _Pragma("unroll") for (int _mi = 0; _mi < 8; ++_mi) {                      \
      acc[_mi][C0] = __builtin_amdgcn_mfma_f32_16x16x32_bf16(                  \
          af[_mi], X0, acc[_mi][C0], 0, 0, 0);                                 \
      acc[_mi][C1] = __builtin_amdgcn_mfma_f32_16x16x32_bf16(                  \
          af[_mi], X1, acc[_mi][C1], 0, 0, 0);                                 \
    }                                                                          \
    __builtin_amdgcn_s_setprio(0);                                             \
  } while (0)

#define TILE4(T, BB)                                                           \
  do {                                                                         \
    const int _t1 = ((T) + 1 < 32) ? (T) + 1 : 31;                             \
    const int _t2 = ((T) + 2 < 32) ? (T) + 2 : 31;                             \
    /* P1: k0,n01 */                                                           \
    LGKM0; MFMA_P(b0, b1, 0, 1);                                               \
    RDB(b2, 2, 0, BB); RDB(b3, 3, 0, BB);                                      \
    STG(0, _t1, 1 - (BB), 1); STG(1, _t1, 1 - (BB), 0);                        \
    __builtin_amdgcn_s_barrier();                                              \
    /* P2: k0,n23 */                                                           \
    LGKM0; MFMA_P(b2, b3, 2, 3);                                               \
    RDA(1, BB); RDB(b0, 0, 1, BB); RDB(b1, 1, 1, BB);                          \
    STG(1, _t1, 1 - (BB), 1);                                                  \
    __builtin_amdgcn_s_barrier();                                              \
    /* P3: k1,n01 */                                                           \
    LGKM0; MFMA_P(b0, b1, 0, 1);                                               \
    RDB(b2, 2, 1, BB); RDB(b3, 3, 1, BB);                                      \
    __builtin_amdgcn_s_barrier();                                              \
    /* P4: k1,n23 */                                                           \
    LGKM0; MFMA_P(b2, b3, 2, 3);                                               \
    STG(0, _t2, (BB), 0);                                                      \
    VM2;                                                                       \
    RDA(0, 1 - (BB)); RDB(b0, 0, 0, 1 - (BB)); RDB(b1, 1, 0, 1 - (BB));        \
    __builtin_amdgcn_s_barrier();                                              \
  } while (0)

__global__ __launch_bounds__(512, 2) void mmd_gemm8(
    const unsigned short* __restrict__ Xb, const unsigned short* __restrict__ Yb,
    const float* __restrict__ x2, const float* __restrict__ y2,
    double* __restrict__ partials) {
  __shared__ __align__(16) unsigned short lds[65536];  // 128 KiB
  __shared__ double red[8];

  const int bid = blockIdx.x;                       // 592 blocks
  const int tid = threadIdx.x;
  const int w = tid >> 6, l = tid & 63;
  const int lr = l & 15, lq = l >> 4;
  const float ce = -1.0f / (2048.0f * 2048.0f);

  if (bid >= 96) {
    // =============================== HEAVY ===============================
    const int hb = bid - 96;
    const int logical = (hb & 7) * 62 + (hb >> 3);
    int ti, tj;
    const unsigned short *Apan, *Bpan;
    const float *rn, *cn;
    double wgt;
    if (logical < 256) {            // XY
      ti = logical & 15; tj = logical >> 4;
      Apan = Xb; Bpan = Yb; rn = x2; cn = y2; wgt = -2.0;
    } else {                        // XX/YY strict-upper off-diagonal
      const int q = logical - 256;
      const int pp = q / 120;
      int jj = q % 120;
      int rr = 0;
      while (jj >= 15 - rr) { jj -= 15 - rr; ++rr; }
      ti = rr; tj = rr + 1 + jj;    // ti < tj
      Apan = Bpan = pp ? Yb : Xb;
      rn = cn = pp ? y2 : x2;
      wgt = 2.0;
    }
    const int i0 = ti << 8, j0 = tj << 8;
    const int wm = w >> 2, wn = w & 3;

    const int ci = w * 128 + l;
    const int rr0 = ci >> 3;
    const int cc0 = (ci & 7) ^ (rr0 & 7);
    const unsigned int sA = (unsigned)(i0 + rr0) * (unsigned)K + (unsigned)(cc0 * 8);
    const unsigned int sB = (unsigned)(j0 + rr0) * (unsigned)K + (unsigned)(cc0 * 8);
    const unsigned int wseg = (unsigned)w * 1024u;

    unsigned int aoff[8], boff[4];
#pragma unroll
    for (int mi = 0; mi < 8; ++mi) {
      const int r = wm * 128 + mi * 16 + lr;
      aoff[mi] = (unsigned)(r * 64 + ((lq ^ (r & 7)) * 8));
    }
#pragma unroll
    for (int ni = 0; ni < 4; ++ni) {
      const int rb = wn * 64 + ni * 16 + lr;
      boff[ni] = (unsigned)(rb * 64 + ((lq ^ (rb & 7)) * 8));
    }

    f32x4 acc[8][4] = {};
    bf16x8 af[8], b0, b1, b2, b3;

    // Prologue: A(0) h0,h1; B(0) h0,h1; A(1) h0 — retire all but A(1)h0,
    // then issue P1's operand reads (waited at the loop's first LGKM0).
    STG(0, 0, 0, 0); STG(0, 0, 0, 1); STG(1, 0, 0, 0); STG(1, 0, 0, 1);
    STG(0, 1, 1, 0);
    VM2;
    __builtin_amdgcn_s_barrier();
    RDA(0, 0); RDB(b0, 0, 0, 0); RDB(b1, 1, 0, 0);

#pragma unroll 1
    for (int tt = 0; tt < 32; tt += 2) {
      TILE4(tt, 0);
      TILE4(tt + 1, 1);
    }

    double s = 0.0;
#pragma unroll
    for (int mi = 0; mi < 8; ++mi) {
#pragma unroll
      for (int r4 = 0; r4 < 4; ++r4) {
        const float rv = rn[i0 + wm * 128 + mi * 16 + lq * 4 + r4];
#pragma unroll
        for (int ni = 0; ni < 4; ++ni) {
          const float cv = cn[j0 + wn * 64 + ni * 16 + lr];
          const float tx = ce * (rv + cv - 2.0f * acc[mi][ni][r4]);
          const float v =
              tx * (1.0f + tx * (0.5f + tx * (0.16666667f + tx * 0.041666668f)));
          s += (double)v;
        }
      }
    }
#pragma unroll
    for (int off = 32; off; off >>= 1) s += __shfl_down(s, off);
    if (l == 0) red[w] = s;
    __syncthreads();
    if (tid == 0) {
      double tot = 0.0;
#pragma unroll
      for (int i = 0; i < 8; ++i) tot += red[i];
      partials[logical] = wgt * tot;
    }
  } else {
    // =============================== LIGHT ===============================
    // diag-quadrant 128^2 jobs; 8 waves of 64x32; LDS: A 0..8192, B 8192..16384
    const int lg2 = (bid & 7) * 12 + (bid >> 3);  // bijective XCD spread (96=8x12)
    const int p = lg2 / 48;
    const int rem = lg2 % 48;
    const int d = rem / 3, sub = rem % 3;
    const double wgt = (sub == 1) ? 2.0 : 1.0;
    const unsigned short* Pan = p ? Yb : Xb;
    const float* nrm = p ? y2 : x2;
    const int i0 = d * 256 + ((sub == 2) ? 128 : 0);
    const int j0 = d * 256 + ((sub >= 1) ? 128 : 0);

    const int m_b = (w >> 2) * 64, n_b = (w & 3) * 32;

    // staging: 1024 16B chunks per operand; thread covers ci0l and ci0l+512
    const int ci0l = w * 64 + l, ci1l = ci0l + 512;
    const int rA0 = ci0l >> 3, cA0 = (ci0l & 7) ^ (rA0 & 7);
    const int rA1 = ci1l >> 3, cA1 = (ci1l & 7) ^ (rA1 & 7);
    const unsigned int sLA0 = (unsigned)(i0 + rA0) * K + (unsigned)(cA0 * 8);
    const unsigned int sLA1 = (unsigned)(i0 + rA1) * K + (unsigned)(cA1 * 8);
    const unsigned int sLB0 = (unsigned)(j0 + rA0) * K + (unsigned)(cA0 * 8);
    const unsigned int sLB1 = (unsigned)(j0 + rA1) * K + (unsigned)(cA1 * 8);
    const unsigned int d0 = (unsigned)w * 512u, d1 = 4096u + (unsigned)w * 512u;

    f32x4 acc2[4][2] = {};

#pragma unroll 1
    for (int k0 = 0; k0 < K; k0 += 64) {
      __builtin_amdgcn_global_load_lds((const AS1 unsigned int*)(Pan + sLA0 + k0),
                                       (AS3 unsigned int*)(lds + d0), 16, 0, 0);
      __builtin_amdgcn_global_load_lds((const AS1 unsigned int*)(Pan + sLA1 + k0),
                                       (AS3 unsigned int*)(lds + d1), 16, 0, 0);
      __builtin_amdgcn_global_load_lds((const AS1 unsigned int*)(Pan + sLB0 + k0),
                                       (AS3 unsigned int*)(lds + 8192u + d0), 16, 0, 0);
      __builtin_amdgcn_global_load_lds((const AS1 unsigned int*)(Pan + sLB1 + k0),
                                       (AS3 unsigned int*)(lds + 8192u + d1), 16, 0, 0);
      __syncthreads();
#pragma unroll
      for (int kk = 0; kk < 64; kk += 32) {
        const int ch = (kk >> 3) + lq;
        bf16x8 a2[4], bb[2];
#pragma unroll
        for (int mi = 0; mi < 4; ++mi) {
          const int r = m_b + mi * 16 + lr;
          a2[mi] = *(const bf16x8*)(lds + r * 64 + ((ch ^ (r & 7)) * 8));
        }
#pragma unroll
        for (int ni = 0; ni < 2; ++ni) {
          const int r = n_b + ni * 16 + lr;
          bb[ni] = *(const bf16x8*)(lds + 8192 + r * 64 + ((ch ^ (r & 7)) * 8));
        }
#pragma unroll
        for (int mi = 0; mi < 4; ++mi)
#pragma unroll
          for (int ni = 0; ni < 2; ++ni)
            acc2[mi][ni] = __builtin_amdgcn_mfma_f32_16x16x32_bf16(
                a2[mi], bb[ni], acc2[mi][ni], 0, 0, 0);
      }
      __syncthreads();
    }

    double s = 0.0;
#pragma unroll
    for (int mi = 0; mi < 4; ++mi) {
#pragma unroll
      for (int r4 = 0; r4 < 4; ++r4) {
        const float rv = nrm[i0 + m_b + mi * 16 + lq * 4 + r4];
#pragma unroll
        for (int ni = 0; ni < 2; ++ni) {
          const float cv = nrm[j0 + n_b + ni * 16 + lr];
          const float tx = ce * (rv + cv - 2.0f * acc2[mi][ni][r4]);
          const float v =
              tx * (1.0f + tx * (0.5f + tx * (0.16666667f + tx * 0.041666668f)));
          s += (double)v;
        }
      }
    }
#pragma unroll
    for (int off = 32; off; off >>= 1) s += __shfl_down(s, off);
    if (l == 0) red[w] = s;
    __syncthreads();
    if (tid == 0) {
      double tot = 0.0;
#pragma unroll
      for (int i = 0; i < 8; ++i) tot += red[i];
      partials[496 + lg2] = wgt * tot;
    }
  }
}

// ---------------- legacy 128^2 kernel (ws-too-small fallback, f32 inputs) ----
__global__ __launch_bounds__(256) void mmd_gemm_f32(
    const float* __restrict__ Xp, const float* __restrict__ Yp,
    const float* __restrict__ x2, const float* __restrict__ y2,
    double* __restrict__ partials) {
  const int p = blockIdx.y;
  const float* Ap = (p == 1) ? Yp : Xp;
  const float* Bp = (p == 0) ? Xp : Yp;
  const float* rn = (p == 1) ? y2 : x2;
  const float* cn = (p == 0) ? x2 : y2;
  const double wgt = (p == 2) ? -2.0 : 1.0;

  const int bx = blockIdx.x;
  const int i0 = (bx & (TILES - 1)) * BM;
  const int j0 = (bx / TILES) * BM;

  __shared__ __align__(16) unsigned short As[BM * 64];
  __shared__ __align__(16) unsigned short Bs[BM * 64];

  const int tid = threadIdx.x;
  const int w = tid >> 6, l = tid & 63;
  const int m_base = (w >> 1) * 64, n_base = (w & 1) * 64;

  f32x4 acc[4][4] = {};

  for (int k0 = 0; k0 < K; k0 += 64) {
#pragma unroll
    for (int u = 0; u < 4; ++u) {
      const int f = u * 256 + tid;
      const int row = f >> 3;
      const int cir = f & 7;
      const int dstb = row * 128 + ((cir ^ (row & 7)) * 16);
      {
        const float* g = Ap + (size_t)(i0 + row) * K + k0 + cir * 8;
        const float4 v0 = *(const float4*)g;
        const float4 v1 = *(const float4*)(g + 4);
        u16x8 o;
        o[0] = f2bf(v0.x); o[1] = f2bf(v0.y); o[2] = f2bf(v0.z); o[3] = f2bf(v0.w);
        o[4] = f2bf(v1.x); o[5] = f2bf(v1.y); o[6] = f2bf(v1.z); o[7] = f2bf(v1.w);
        *(u16x8*)((char*)As + dstb) = o;
      }
      {
        const float* g = Bp + (size_t)(j0 + row) * K + k0 + cir * 8;
        const float4 v0 = *(const float4*)g;
        const float4 v1 = *(const float4*)(g + 4);
        u16x8 o;
        o[0] = f2bf(v0.x); o[1] = f2bf(v0.y); o[2] = f2bf(v0.z); o[3] = f2bf(v0.w);
        o[4] = f2bf(v1.x); o[5] = f2bf(v1.y); o[6] = f2bf(v1.z); o[7] = f2bf(v1.w);
        *(u16x8*)((char*)Bs + dstb) = o;
      }
    }
    __syncthreads();

#pragma unroll
    for (int kk = 0; kk < 64; kk += 32) {
      bf16x8 af2[4], bfr[4];
      const int lr = l & 15;
      const int ch = (kk >> 3) + (l >> 4);
#pragma unroll
      for (int mi = 0; mi < 4; ++mi) {
        const int r = m_base + mi * 16 + lr;
        af2[mi] = *(const bf16x8*)((const char*)As + r * 128 + ((ch ^ (r & 7)) * 16));
      }
#pragma unroll
      for (int ni = 0; ni < 4; ++ni) {
        const int r = n_base + ni * 16 + lr;
        bfr[ni] = *(const bf16x8*)((const char*)Bs + r * 128 + ((ch ^ (r & 7)) * 16));
      }
#pragma unroll
      for (int mi = 0; mi < 4; ++mi)
#pragma unroll
        for (int ni = 0; ni < 4; ++ni)
          acc[mi][ni] = __builtin_amdgcn_mfma_f32_16x16x32_bf16(
              af2[mi], bfr[ni], acc[mi][ni], 0, 0, 0);
    }
    __syncthreads();
  }

  const float ce = -1.0f / (2048.0f * 2048.0f);
  double s = 0.0;
  const int lr = l & 15, lq = l >> 4;
#pragma unroll
  for (int mi = 0; mi < 4; ++mi) {
#pragma unroll
    for (int r4 = 0; r4 < 4; ++r4) {
      const float rv = rn[i0 + m_base + mi * 16 + lq * 4 + r4];
#pragma unroll
      for (int ni = 0; ni < 4; ++ni) {
        const float cv = cn[j0 + n_base + ni * 16 + lr];
        const float tx = ce * (rv + cv - 2.0f * acc[mi][ni][r4]);
        const float v =
            tx * (1.0f + tx * (0.5f + tx * (0.16666667f + tx * 0.041666668f)));
        s += (double)v;
      }
    }
  }
#pragma unroll
  for (int off = 32; off; off >>= 1) s += __shfl_down(s, off);
  __shared__ double red[4];
  if (l == 0) red[w] = s;
  __syncthreads();
  if (tid == 0) partials[p * NBLK + bx] = wgt * (red[0] + red[1] + red[2] + red[3]);
}

__global__ __launch_bounds__(256) void finalize_kernel(
    const double* __restrict__ partials, float* __restrict__ out, int n) {
  double s = 0.0;
  for (int i = threadIdx.x; i < n; i += 256) s += partials[i];
#pragma unroll
  for (int off = 32; off; off >>= 1) s += __shfl_down(s, off);
  __shared__ double red[4];
  if ((threadIdx.x & 63) == 0) red[threadIdx.x >> 6] = s;
  __syncthreads();
  if (threadIdx.x == 0)
    out[0] = (float)((red[0] + red[1] + red[2] + red[3]) *
                     (1.0 / ((double)N * (double)N)));
}

extern "C" void kernel_launch(void* const* d_in, const int* in_sizes, int n_in,
                              void* d_out, int out_size, void* d_ws,
                              size_t ws_size, hipStream_t stream) {
  const float* X = (const float*)d_in[0];
  const float* Y = (const float*)d_in[1];
  char* ws = (char*)d_ws;

  double* partials = (double*)ws;           // fast: 592 f64; fallback: 3072
  float* x2 = (float*)(ws + 24576);
  float* y2 = (float*)(ws + 24576 + 16384);
  unsigned short* Xb = (unsigned short*)(ws + 65536);
  unsigned short* Yb = Xb + (size_t)N * K;
  const size_t need_fast = (size_t)65536 + (size_t)2 * N * K * 2;
  const bool fast = ws_size >= need_fast;

  prep_kernel<<<dim3(N, 2), 256, 0, stream>>>(X, Y, x2, y2, Xb, Yb, fast ? 1 : 0);
  if (fast) {
    mmd_gemm8<<<dim3(592), dim3(512), 0, stream>>>(Xb, Yb, x2, y2, partials);
    finalize_kernel<<<1, 256, 0, stream>>>(partials, (float*)d_out, 592);
  } else {
    mmd_gemm_f32<<<dim3(NBLK, 3), 256, 0, stream>>>(X, Y, x2, y2, partials);
    finalize_kernel<<<1, 256, 0, stream>>>(partials, (float*)d_out, 3072);
  }
}